// Round 1
// 895.895 us; speedup vs baseline: 1.0101x; 1.0101x over previous
//
#include <hip/hip_runtime.h>
#include <hip/hip_bf16.h>
#include <cmath>

#define BATCH   16384
#define NT      26
#define VOCAB_N 100000
#define EMB_D   64
#define LOOK    4

typedef __attribute__((ext_vector_type(8))) short  short8;   // 8 bf16 = 4 VGPRs
typedef __attribute__((ext_vector_type(4))) float  float4v;  // MFMA C/D frag

#define GLOBAL_AS __attribute__((address_space(1)))
#define LDS_AS    __attribute__((address_space(3)))

// bf16 round-to-nearest-even, bit-level (no header API dependency)
static __device__ __forceinline__ short f32_to_bf16_bits(float f) {
    unsigned u = __builtin_bit_cast(unsigned, f);
    unsigned r = (u + 0x7fffu + ((u >> 16) & 1u)) >> 16;
    return (short)r;
}
static __device__ __forceinline__ float bf16_bits_to_f32(short s) {
    return __builtin_bit_cast(float, ((unsigned)(unsigned short)s) << 16);
}

// ---------------------------------------------------------------------------
// Fused fp32 → bf16 weight conversion for all 4 weight tensors (1 launch).
// Segments: wb1 256x512 | wb2 64x256 | wt0 512x415 -> padded 512x416 | wt1 256x512
// ---------------------------------------------------------------------------
__global__ __launch_bounds__(256) void conv_all(
    const float* __restrict__ bW1, const float* __restrict__ bW2,
    const float* __restrict__ tW0, const float* __restrict__ tW1,
    __hip_bfloat16* __restrict__ wb1, __hip_bfloat16* __restrict__ wb2,
    __hip_bfloat16* __restrict__ wt0, __hip_bfloat16* __restrict__ wt1)
{
    int i = blockIdx.x * 256 + threadIdx.x;
    if (i < 131072) { wb1[i] = __float2bfloat16(bW1[i]); return; }
    i -= 131072;
    if (i < 16384)  { wb2[i] = __float2bfloat16(bW2[i]); return; }
    i -= 16384;
    if (i < 212992) {
        int r = i / 416, k = i % 416;
        wt0[i] = __float2bfloat16(k < 415 ? tW0[(size_t)r * 415 + k] : 0.f);
        return;
    }
    i -= 212992;
    if (i < 131072) wt1[i] = __float2bfloat16(tW1[i]);
}

// ---------------------------------------------------------------------------
// fp32 vector GEMM (small K only: bottom layer 0, K=13), bf16 output.
// Y = relu(X @ W^T + b).  BM=128, BN=128, TM=TN=8, BK=16.
// ---------------------------------------------------------------------------
__global__ __launch_bounds__(256) void gemm_f32_k13(
    const float* __restrict__ X, const float* __restrict__ W,
    const float* __restrict__ bias, __hip_bfloat16* __restrict__ Y,
    int M, int N, int K)
{
    constexpr int BM = 128, BN = 128, BK = 16, TM = 8, TN = 8, PAD = 4;
    __shared__ __align__(16) float Xs[BK][BM + PAD];
    __shared__ __align__(16) float Ws[BK][BN + PAD];

    const int tid = threadIdx.x;
    const int tx  = tid % (BN / TN);
    const int ty  = tid / (BN / TN);
    const int m0  = blockIdx.y * BM;
    const int n0  = blockIdx.x * BN;

    float acc[TM][TN];
    #pragma unroll
    for (int i = 0; i < TM; i++)
        #pragma unroll
        for (int j = 0; j < TN; j++) acc[i][j] = 0.f;

    for (int k0 = 0; k0 < K; k0 += BK) {
        for (int idx = tid; idx < BM * BK; idx += 256) {
            int r = idx / BK, k = idx % BK, gk = k0 + k;
            Xs[k][r] = (gk < K) ? X[(size_t)(m0 + r) * K + gk] : 0.f;
        }
        for (int idx = tid; idx < BN * BK; idx += 256) {
            int r = idx / BK, k = idx % BK, gk = k0 + k;
            Ws[k][r] = (gk < K) ? W[(size_t)(n0 + r) * K + gk] : 0.f;
        }
        __syncthreads();
        #pragma unroll
        for (int kk = 0; kk < BK; kk++) {
            float a[TM], bb[TN];
            #pragma unroll
            for (int i = 0; i < TM; i++) a[i] = Xs[kk][ty * TM + i];
            #pragma unroll
            for (int j = 0; j < TN; j++) bb[j] = Ws[kk][tx * TN + j];
            #pragma unroll
            for (int i = 0; i < TM; i++)
                #pragma unroll
                for (int j = 0; j < TN; j++)
                    acc[i][j] += a[i] * bb[j];
        }
        __syncthreads();
    }
    #pragma unroll
    for (int i = 0; i < TM; i++) {
        int m = m0 + ty * TM + i;
        #pragma unroll
        for (int j = 0; j < TN; j++) {
            int n = n0 + tx * TN + j;
            float v = fmaxf(acc[i][j] + bias[n], 0.f);
            Y[(size_t)m * N + n] = __float2bfloat16(v);
        }
    }
}

// ---------------------------------------------------------------------------
// bf16 MFMA GEMM: Y = act(X @ W^T + bias)
// X: M x K bf16 row-major.  W: N x K bf16 row-major.  K % 32 == 0.
// Verified lane maps (learn_hip m89/m91): A[m=lane&15][k=(lane>>4)*8+j],
// B[k][n]: n=lane&15, k=(lane>>4)*8+j;  C/D: col=lane&15, row=(lane>>4)*4+reg.
// ---------------------------------------------------------------------------
template<int BN, int WM, int WN, int RELU, int OUT_BF16>
__global__ __launch_bounds__(256) void mfma_gemm(
    const short* __restrict__ A, const short* __restrict__ W,
    const float* __restrict__ bias, void* __restrict__ Y,
    int M, int N, int K)
{
    constexpr int BM = 128, BK = 32;
    constexpr int FM = BM / WM / 16;       // frag rows per wave
    constexpr int FN = BN / WN / 16;       // frag cols per wave
    constexpr int ACH = (BM * BK * 2) / 1024;   // A chunks of 1KB (=8)
    constexpr int BCH = (BN * BK * 2) / 1024;   // B chunks (8 or 4)

    __shared__ short As[BM * BK];
    __shared__ short Bs[BN * BK];

    const int tid  = threadIdx.x;
    const int wave = tid >> 6;
    const int lane = tid & 63;
    const int wm   = wave / WN;
    const int wn   = wave % WN;
    const int m0   = blockIdx.y * BM;
    const int n0   = blockIdx.x * BN;

    const int r16 = lane >> 2;        // row within a 16-row chunk
    const int c16 = (lane & 3) * 8;   // short offset of this lane's 16B

    float4v acc[FM][FN];
    #pragma unroll
    for (int i = 0; i < FM; i++)
        #pragma unroll
        for (int j = 0; j < FN; j++) acc[i][j] = (float4v)(0.f);

    for (int k0 = 0; k0 < K; k0 += BK) {
        #pragma unroll
        for (int c = 0; c < ACH / 4; c++) {
            int chunk = wave * (ACH / 4) + c;
            int row   = chunk * 16 + r16;
            const short* src = A + (size_t)(m0 + row) * K + k0 + c16;
            __builtin_amdgcn_global_load_lds(
                (const GLOBAL_AS void*)src,
                (LDS_AS void*)(As + chunk * 512), 16, 0, 0);
        }
        #pragma unroll
        for (int c = 0; c < BCH / 4; c++) {
            int chunk = wave * (BCH / 4) + c;
            int row   = chunk * 16 + r16;
            const short* src = W + (size_t)(n0 + row) * K + k0 + c16;
            __builtin_amdgcn_global_load_lds(
                (const GLOBAL_AS void*)src,
                (LDS_AS void*)(Bs + chunk * 512), 16, 0, 0);
        }
        __syncthreads();

        short8 a_frag[FM], b_frag[FN];
        const int kq = (lane >> 4) * 8;
        #pragma unroll
        for (int fi = 0; fi < FM; fi++) {
            int m_local = wm * (BM / WM) + fi * 16 + (lane & 15);
            a_frag[fi] = *(const short8*)(As + m_local * BK + kq);
        }
        #pragma unroll
        for (int fj = 0; fj < FN; fj++) {
            int n_local = wn * (BN / WN) + fj * 16 + (lane & 15);
            b_frag[fj] = *(const short8*)(Bs + n_local * BK + kq);
        }
        #pragma unroll
        for (int fi = 0; fi < FM; fi++)
            #pragma unroll
            for (int fj = 0; fj < FN; fj++)
                acc[fi][fj] = __builtin_amdgcn_mfma_f32_16x16x32_bf16(
                    a_frag[fi], b_frag[fj], acc[fi][fj], 0, 0, 0);

        __syncthreads();
    }

    #pragma unroll
    for (int fi = 0; fi < FM; fi++) {
        #pragma unroll
        for (int fj = 0; fj < FN; fj++) {
            int col   = n0 + wn * (BN / WN) + fj * 16 + (lane & 15);
            int rbase = m0 + wm * (BM / WM) + fi * 16 + (lane >> 4) * 4;
            float bv  = bias[col];
            #pragma unroll
            for (int r = 0; r < 4; r++) {
                float v = acc[fi][fj][r] + bv;
                if (RELU) v = fmaxf(v, 0.f);
                if (OUT_BF16)
                    ((__hip_bfloat16*)Y)[(size_t)(rbase + r) * N + col] =
                        __float2bfloat16(v);
                else
                    ((float*)Y)[(size_t)(rbase + r) * N + col] = v;
            }
        }
    }
}

// ---------------------------------------------------------------------------
// Embedding gather + pairwise interaction → R (bf16, stride 416, col415 = 0)
//
// v2: - gather vectorized (dwordx4; 16 lanes per 256B row; 8 loads in
//       flight per thread for memory-level parallelism)
//     - pairwise Z = T·T^T computed with MFMA (3 tiles of 16x16x32 bf16,
//       one per wave) using a hi/lo bf16 split of T:
//       Z ≈ hi·hi^T + hi·lo^T + lo·hi^T  (rel err ~2^-17, far below the
//       2^-9 bf16 rounding R already carries). Replaces 360 KB/block of
//       conflicted scalar ds_read_b32 with ~16 KB of conflict-free b128.
// ---------------------------------------------------------------------------
#define TS 68   // fp32 row stride (64 + 4 pad)

__global__ __launch_bounds__(256) void interact_kernel(
    const float* __restrict__ x2,    // B x 64 fp32
    const int*   __restrict__ lS_i,  // NT x (B*LOOK)
    const float* __restrict__ emb,   // NT x VOCAB x 64
    __hip_bfloat16* __restrict__ R)  // B x 416 bf16
{
    __shared__ __align__(16) float T[32 * TS];   // rows 0..26 used, 27..31 zero
    __shared__ int sidx[NT * LOOK];

    const int b   = blockIdx.x;
    const int tid = threadIdx.x;

    if (tid < NT * LOOK) {
        int tb = tid >> 2, l = tid & 3;
        sidx[tid] = lS_i[(size_t)tb * (BATCH * LOOK) + (size_t)b * LOOK + l];
    }
    if (tid < 16) {  // row 0 = dense feature x
        *(float4*)(&T[tid * 4]) = *(const float4*)(x2 + (size_t)b * EMB_D + tid * 4);
    }
    // zero pad rows 27..31 (MFMA reads them; outputs there are discarded,
    // but keep them finite)
    for (int i = 27 * TS + tid; i < 32 * TS; i += 256) T[i] = 0.f;
    __syncthreads();

    // ---- gather: 16 groups of 16 threads; group handles one table ----
    const int c4 = (tid & 15) * 4;
    #pragma unroll
    for (int it = 0; it < 2; ++it) {
        int tb = (tid >> 4) + it * 16;
        if (tb < NT) {
            float4 s = {0.f, 0.f, 0.f, 0.f};
            #pragma unroll
            for (int l = 0; l < LOOK; l++) {
                int row = sidx[tb * LOOK + l];
                float4 v = *(const float4*)(emb +
                    ((size_t)tb * VOCAB_N + row) * EMB_D + c4);
                s.x += v.x; s.y += v.y; s.z += v.z; s.w += v.w;
            }
            *(float4*)(&T[(tb + 1) * TS + c4]) = s;
        }
    }
    __syncthreads();

    const int wave = tid >> 6;
    const int lane = tid & 63;
    __hip_bfloat16* Rb = R + (size_t)b * 416;

    if (wave < 3) {
        // tile (ti,tj) of C = T·T^T:  wave0 -> (0,0), wave1 -> (1,0), wave2 -> (1,1)
        const int ti = (wave == 0) ? 0 : 1;
        const int tj = (wave == 2) ? 1 : 0;

        // load + hi/lo split fragments for both row-tiles
        short8 fhi[2][2], flo[2][2];   // [rowtile][kstep]
        const int r  = lane & 15;
        const int kq = (lane >> 4) * 8;
        #pragma unroll
        for (int rt = 0; rt < 2; rt++) {
            #pragma unroll
            for (int kk = 0; kk < 2; kk++) {
                const float* src = &T[(rt * 16 + r) * TS + kk * 32 + kq];
                float4 v0 = *(const float4*)(src);
                float4 v1 = *(const float4*)(src + 4);
                float vv[8] = {v0.x, v0.y, v0.z, v0.w, v1.x, v1.y, v1.z, v1.w};
                short8 h, l;
                #pragma unroll
                for (int j = 0; j < 8; j++) {
                    short hb = f32_to_bf16_bits(vv[j]);
                    float hf = bf16_bits_to_f32(hb);
                    short lb = f32_to_bf16_bits(vv[j] - hf);
                    h[j] = hb; l[j] = lb;
                }
                fhi[rt][kk] = h; flo[rt][kk] = l;
            }
        }

        float4v acc = (float4v)(0.f);
        #pragma unroll
        for (int kk = 0; kk < 2; kk++) {
            acc = __builtin_amdgcn_mfma_f32_16x16x32_bf16(
                      fhi[ti][kk], fhi[tj][kk], acc, 0, 0, 0);
            acc = __builtin_amdgcn_mfma_f32_16x16x32_bf16(
                      fhi[ti][kk], flo[tj][kk], acc, 0, 0, 0);
            acc = __builtin_amdgcn_mfma_f32_16x16x32_bf16(
                      flo[ti][kk], fhi[tj][kk], acc, 0, 0, 0);
        }

        // C/D: col = lane&15, row = (lane>>4)*4 + reg
        const int gj = tj * 16 + (lane & 15);
        #pragma unroll
        for (int rr = 0; rr < 4; rr++) {
            int gi = ti * 16 + (lane >> 4) * 4 + rr;
            if (gi < NT + 1 && gi > gj) {
                int p = gi * (gi - 1) / 2 + gj;
                Rb[64 + p] = __float2bfloat16(acc[rr]);
            }
        }
    } else {
        // wave 3: copy dense feature row + zero pad column
        Rb[lane] = __float2bfloat16(T[lane]);
        if (lane == 0) Rb[415] = __float2bfloat16(0.f);
    }
}

// ---------------------------------------------------------------------------
// Final layer: out[b] = sigmoid(dot(z1[b,:256], W2) + b2). Wave per sample.
// ---------------------------------------------------------------------------
__global__ __launch_bounds__(256) void top_final(
    const float* __restrict__ z1, const float* __restrict__ W2,
    const float* __restrict__ b2, float* __restrict__ out)
{
    const int wave = threadIdx.x >> 6;
    const int lane = threadIdx.x & 63;
    const int b = blockIdx.x * 4 + wave;

    float s = 0.f;
    #pragma unroll
    for (int q = 0; q < 4; q++) {
        int k = q * 64 + lane;
        s += z1[(size_t)b * 256 + k] * W2[k];
    }
    #pragma unroll
    for (int off = 32; off; off >>= 1) s += __shfl_down(s, off, 64);
    if (lane == 0) out[b] = 1.f / (1.f + expf(-(s + b2[0])));
}

// ---------------------------------------------------------------------------
// Input order: 0 dense_x 1 lS_o 2 lS_i 3 emb | 4 bW0 5 bb0 6 tW0 7 tb0
//              8 bW1 9 bb1 10 tW1 11 tb1 | 12 bW2 13 bb2 14 tW2 15 tb2
// ---------------------------------------------------------------------------
extern "C" void kernel_launch(void* const* d_in, const int* in_sizes, int n_in,
                              void* d_out, int out_size, void* d_ws, size_t ws_size,
                              hipStream_t stream)
{
    const float* dense = (const float*)d_in[0];
    const int*   lS_i  = (const int*)d_in[2];
    const float* emb   = (const float*)d_in[3];
    const float* bW0 = (const float*)d_in[4];  const float* bb0 = (const float*)d_in[5];
    const float* tW0 = (const float*)d_in[6];  const float* tb0 = (const float*)d_in[7];
    const float* bW1 = (const float*)d_in[8];  const float* bb1 = (const float*)d_in[9];
    const float* tW1 = (const float*)d_in[10]; const float* tb1 = (const float*)d_in[11];
    const float* bW2 = (const float*)d_in[12]; const float* bb2 = (const float*)d_in[13];
    const float* tW2 = (const float*)d_in[14]; const float* tb2 = (const float*)d_in[15];
    float* out = (float*)d_out;

    // workspace layout
    char* p = (char*)d_ws;
    __hip_bfloat16* x0_bf = (__hip_bfloat16*)p;  p += (size_t)BATCH * 512 * 2;
    __hip_bfloat16* x1_bf = (__hip_bfloat16*)p;  p += (size_t)BATCH * 256 * 2;
    float*          x2_f  = (float*)p;           p += (size_t)BATCH * 64  * 4;
    __hip_bfloat16* R_bf  = (__hip_bfloat16*)p;  p += (size_t)BATCH * 416 * 2;
    __hip_bfloat16* z0_bf = (__hip_bfloat16*)p;  p += (size_t)BATCH * 512 * 2;
    float*          z1_f  = (float*)p;           p += (size_t)BATCH * 256 * 4;
    __hip_bfloat16* wb1   = (__hip_bfloat16*)p;  p += (size_t)256 * 512 * 2;
    __hip_bfloat16* wb2   = (__hip_bfloat16*)p;  p += (size_t)64  * 256 * 2;
    __hip_bfloat16* wt0   = (__hip_bfloat16*)p;  p += (size_t)512 * 416 * 2;
    __hip_bfloat16* wt1   = (__hip_bfloat16*)p;  p += (size_t)256 * 512 * 2;

    dim3 blk(256);

    // fused weight conversions (every call — ws is re-poisoned)
    conv_all<<<dim3(1920), blk, 0, stream>>>(bW1, bW2, tW0, tW1, wb1, wb2, wt0, wt1);

    // bottom MLP
    gemm_f32_k13<<<dim3(512 / 128, BATCH / 128), blk, 0, stream>>>(
        dense, bW0, bb0, x0_bf, BATCH, 512, 13);
    mfma_gemm<128, 2, 2, 1, 1><<<dim3(256 / 128, BATCH / 128), blk, 0, stream>>>(
        (const short*)x0_bf, (const short*)wb1, bb1, x1_bf, BATCH, 256, 512);
    mfma_gemm<64, 4, 1, 1, 0><<<dim3(1, BATCH / 128), blk, 0, stream>>>(
        (const short*)x1_bf, (const short*)wb2, bb2, x2_f, BATCH, 64, 256);

    // embedding + interaction (writes bf16 R, K padded to 416)
    interact_kernel<<<dim3(BATCH), blk, 0, stream>>>(x2_f, lS_i, emb, R_bf);

    // top MLP
    mfma_gemm<128, 2, 2, 1, 1><<<dim3(512 / 128, BATCH / 128), blk, 0, stream>>>(
        (const short*)R_bf, (const short*)wt0, tb0, z0_bf, BATCH, 512, 416);
    mfma_gemm<128, 2, 2, 1, 0><<<dim3(256 / 128, BATCH / 128), blk, 0, stream>>>(
        (const short*)z0_bf, (const short*)wt1, tb1, z1_f, BATCH, 256, 512);
    top_final<<<dim3(BATCH / 4), blk, 0, stream>>>(z1_f, tW2, tb2, out);
}